// Round 4
// baseline (424.296 us; speedup 1.0000x reference)
//
#include <hip/hip_runtime.h>
#include <hip/hip_bf16.h>
#include <math.h>

typedef __attribute__((ext_vector_type(4))) float  f32x4;
typedef __attribute__((ext_vector_type(8))) __bf16 bf16x8;
typedef __attribute__((ext_vector_type(4))) unsigned int u32x4;

__device__ __forceinline__ unsigned short f2bu(float x) {
    __bf16 h = (__bf16)x;
    return __builtin_bit_cast(unsigned short, h);
}

__device__ __forceinline__ f32x4 MF(bf16x8 a, bf16x8 b, f32x4 c) {
    return __builtin_amdgcn_mfma_f32_16x16x32_bf16(a, b, c, 0, 0, 0);
}

__device__ __forceinline__ f32x4 zero4() { f32x4 z = {0.f, 0.f, 0.f, 0.f}; return z; }

// B-fragment (BT row-major, contiguous K): lane holds BT[row][k0..k0+7], f32 -> bf16
__device__ __forceinline__ bf16x8 bfrag_g(const float* W, int ldk, int row, int k0) {
    const float* p = W + (size_t)row * ldk + k0;
    bf16x8 r;
#pragma unroll
    for (int e = 0; e < 8; ++e) r[e] = (__bf16)p[e];
    return r;
}

// ---- LDS layout (bytes), M=32 atoms/tile, two ping-pong bf16 sets + f32 stage ----
// per set: VIN 3*32*256 = 24576 ; H 32*512 = 16384  -> SET_SZ 40960
#define SET_SZ   40960
#define VIN_OFF  0
#define H_OFF    24576
#define S1_OFF   81920   // 32*256 = 8192
#define RED_OFF  90112   // 8 waves * 32 f32 = 1024
#define VSTG     91136   // V f32 stage: 32*384*4 = 49152
#define SSTG     140288  // S f32 stage: 32*128*4 = 16384
#define LDS_BYTES 156672

// A-fragment read from swizzled LDS tile
__device__ __forceinline__ bf16x8 afrag(const unsigned char* base, int rb, int row, int kb) {
    u32x4 q = *(const u32x4*)(base + row * rb + (kb ^ ((row & 7) << 4)));
    return __builtin_bit_cast(bf16x8, q);
}

__device__ __forceinline__ unsigned long long pack4bf(f32x4 x) {
    return (unsigned long long)f2bu(x[0])
         | ((unsigned long long)f2bu(x[1]) << 16)
         | ((unsigned long long)f2bu(x[2]) << 32)
         | ((unsigned long long)f2bu(x[3]) << 48);
}

// DMA tile t's V+S (f32) into the LDS staging area. Zero VGPR cost.
// Per wave: uniform LDS base + lane*16B (HW rule); global src is per-lane.
__device__ __forceinline__ void issue_dma(const float* __restrict__ S,
                                          const float* __restrict__ V,
                                          int t, int tid, int wv,
                                          unsigned char* lds) {
    const float* vsrc = V + (size_t)t * (32 * 384);
    const float* ssrc = S + (size_t)t * (32 * 128);
#pragma unroll
    for (int j = 0; j < 6; ++j)
        __builtin_amdgcn_global_load_lds((const void*)(vsrc + ((tid + (j << 9)) << 2)),
                                         (void*)(lds + VSTG + (j << 13) + (wv << 10)),
                                         16, 0, 0);
#pragma unroll
    for (int j = 0; j < 2; ++j)
        __builtin_amdgcn_global_load_lds((const void*)(ssrc + ((tid + (j << 9)) << 2)),
                                         (void*)(lds + SSTG + (j << 13) + (wv << 10)),
                                         16, 0, 0);
}

// Convert staged f32 tile -> swizzled bf16 tiles in dstSet (VIN + H s-half).
__device__ __forceinline__ void cvt_tile(unsigned char* lds, unsigned char* dstSet, int tid) {
#pragma unroll
    for (int j = 0; j < 6; ++j) {
        int c = tid + (j << 9);
        f32x4 x = *(const f32x4*)(lds + VSTG + (c << 4));
        int row = c / 96, rem = c - row * 96;
        int d = rem >> 5, c4 = rem & 31;
        *(unsigned long long*)(dstSet + VIN_OFF + (d << 13) + row * 256 +
                               ((c4 << 3) ^ ((row & 7) << 4))) = pack4bf(x);
    }
#pragma unroll
    for (int j = 0; j < 2; ++j) {
        int c = tid + (j << 9);
        f32x4 x = *(const f32x4*)(lds + SSTG + (c << 4));
        int row = c >> 5, c4 = c & 31;
        *(unsigned long long*)(dstSet + H_OFF + row * 512 +
                               ((c4 << 3) ^ ((row & 7) << 4))) = pack4bf(x);
    }
}

__global__ __launch_bounds__(512, 2) void eqsc_main(
    const float* __restrict__ S, const float* __restrict__ V,
    const float* __restrict__ u0w, const float* __restrict__ v0w,
    const float* __restrict__ a0w1, const float* __restrict__ a0b1,
    const float* __restrict__ a0w2, const float* __restrict__ a0b2,
    const float* __restrict__ u1w, const float* __restrict__ v1w,
    const float* __restrict__ a1w1, const float* __restrict__ a1b1,
    const float* __restrict__ a1w2, const float* __restrict__ a1b2,
    const float* __restrict__ outw, const float* __restrict__ outbp,
    float* __restrict__ sOut, int NT)
{
    __shared__ __align__(16) unsigned char lds[LDS_BYTES];
    const int tid  = threadIdx.x;
    const int lane = tid & 63;
    const int wv   = tid >> 6;
    const int l15  = lane & 15;
    const int lg   = lane >> 4;
    const int grow = wv * 16 + l15;   // this wave/lane's output feature column
    const int kbb  = lg << 4;         // k-byte base within a 64B kt chunk

    // ---- folded readout: wfold[k] = sum_g a1w2[g,k]*outw[g]; cfold = b2g1.outw + outb
    float wf = 0.f, cf = 0.f;
    for (int g = 0; g < 128; ++g) {
        float og = outw[g];
        wf += a1w2[g * 128 + grow] * og;
        cf += a1b2[g] * og;
    }
    cf += outbp[0];

    // ---- persistent weight fragments (bf16, register-resident): 144 VGPRs ----
    bf16x8 uw0f[4], vw0f[4], w2g0[4], w2s0[4], vw1f[4];
    bf16x8 w1f0[8], w1f1[8];
#pragma unroll
    for (int kt = 0; kt < 4; ++kt) {
        int k0 = kt * 32 + lg * 8;
        uw0f[kt] = bfrag_g(u0w, 128, grow, k0);
        vw0f[kt] = bfrag_g(v0w, 128, grow, k0);
        w2g0[kt] = bfrag_g(a0w2, 128, grow, k0);
        w2s0[kt] = bfrag_g(a0w2, 128, 128 + grow, k0);
        vw1f[kt] = bfrag_g(v1w, 128, grow, k0);
    }
#pragma unroll
    for (int kt = 0; kt < 8; ++kt) {
        int k0 = kt * 32 + lg * 8;
        w1f0[kt] = bfrag_g(a0w1, 256, grow, k0);
        w1f1[kt] = bfrag_g(a1w1, 256, grow, k0);
    }
    const float b1_0 = a0b1[grow];
    const float b2g0 = a0b2[grow];
    const float b2s0 = a0b2[128 + grow];
    const float b1_1 = a1b1[grow];

    const int stride = gridDim.x;
    const int t0 = blockIdx.x;

    // ---- prologue: DMA tile t0 -> stage; barrier drains vmcnt; cvt into set 0 ----
    if (t0 < NT) issue_dma(S, V, t0, tid, wv, lds);
    __syncthreads();
    if (t0 < NT) cvt_tile(lds, lds, tid);
    __syncthreads();

    int i = 0;
    for (int ty = t0; ty < NT + stride; ty += stride, ++i) {
        const bool yv = (ty < NT);
        const bool xv = (i > 0);
        const int  tz = ty + stride;
        const bool zv = (tz < NT);
        unsigned char* Lsy = lds + (i & 1) * SET_SZ;
        unsigned char* Lsx = lds + ((i & 1) ^ 1) * SET_SZ;

        // ======== slot 1: DMA(Z) ; Y.P1 (L0 v-phase) || X.P4 (L1 v-phase) ========
        if (zv) issue_dma(S, V, tz, tid, wv, lds);

        f32x4 v1a[2][3];
        if (yv) {
#pragma unroll
            for (int m = 0; m < 2; ++m) {
                const int mr = m << 4;
                f32x4 n2 = zero4();
#pragma unroll
                for (int d = 0; d < 3; ++d) {
                    f32x4 a1 = zero4(), a2 = zero4();
#pragma unroll
                    for (int kt = 0; kt < 4; ++kt) {
                        bf16x8 a = afrag(Lsy + VIN_OFF + (d << 13), 256, mr + l15, (kt << 6) + kbb);
                        a1 = MF(a, uw0f[kt], a1);
                        a2 = MF(a, vw0f[kt], a2);
                    }
                    v1a[m][d] = a1;
#pragma unroll
                    for (int e = 0; e < 4; ++e) { float x = a2[e] + 1e-8f; n2[e] += x * x; }
                }
#pragma unroll
                for (int e = 0; e < 4; ++e) {
                    int row = mr + (lg << 2) + e;
                    *(unsigned short*)(Lsy + H_OFF + row * 512 +
                        ((256 + (grow << 1)) ^ ((row & 7) << 4))) = f2bu(sqrtf(n2[e]));
                }
            }
        }
        if (xv) {
#pragma unroll
            for (int m = 0; m < 2; ++m) {
                const int mr = m << 4;
                f32x4 n2 = zero4();
#pragma unroll
                for (int d = 0; d < 3; ++d) {
                    f32x4 acc = zero4();
#pragma unroll
                    for (int kt = 0; kt < 4; ++kt)
                        acc = MF(afrag(Lsx + VIN_OFF + (d << 13), 256, mr + l15, (kt << 6) + kbb),
                                 vw1f[kt], acc);
#pragma unroll
                    for (int e = 0; e < 4; ++e) { float x = acc[e] + 1e-8f; n2[e] += x * x; }
                }
#pragma unroll
                for (int e = 0; e < 4; ++e) {
                    int row = mr + (lg << 2) + e;
                    *(unsigned short*)(Lsx + H_OFF + row * 512 +
                        ((256 + (grow << 1)) ^ ((row & 7) << 4))) = f2bu(sqrtf(n2[e]));
                }
            }
        }
        __syncthreads();   // also drains the Z DMA (compiler emits vmcnt(0))

        // ======== slot 2: Y.P2 (L0 MLP1) || X.P5 (L1 MLP1 + folded readout) ========
        if (yv) {
#pragma unroll
            for (int m = 0; m < 2; ++m) {
                const int mr = m << 4;
                f32x4 acc = zero4();
#pragma unroll
                for (int kt = 0; kt < 8; ++kt)
                    acc = MF(afrag(Lsy + H_OFF, 512, mr + l15, (kt << 6) + kbb), w1f0[kt], acc);
#pragma unroll
                for (int e = 0; e < 4; ++e) {
                    float x = acc[e] + b1_0;
                    float y = x / (1.f + __expf(-x));
                    int row = mr + (lg << 2) + e;
                    *(unsigned short*)(lds + S1_OFF + row * 256 +
                        ((grow << 1) ^ ((row & 7) << 4))) = f2bu(y);
                }
            }
        }
        if (xv) {
#pragma unroll
            for (int m = 0; m < 2; ++m) {
                const int mr = m << 4;
                f32x4 acc = zero4();
#pragma unroll
                for (int kt = 0; kt < 8; ++kt)
                    acc = MF(afrag(Lsx + H_OFF, 512, mr + l15, (kt << 6) + kbb), w1f1[kt], acc);
                float p[4];
#pragma unroll
                for (int e = 0; e < 4; ++e) {
                    float x = acc[e] + b1_1;
                    float y = x / (1.f + __expf(-x));
                    p[e] = y * wf;                 // folded (w2g1^T @ outw) readout, f32
                }
#pragma unroll
                for (int off = 1; off < 16; off <<= 1) {
#pragma unroll
                    for (int e = 0; e < 4; ++e) p[e] += __shfl_xor(p[e], off);
                }
                if (l15 == 0) {
#pragma unroll
                    for (int e = 0; e < 4; ++e)
                        *((float*)(lds + RED_OFF) + (wv << 5) + mr + (lg << 2) + e) = p[e];
                }
            }
        }
        __syncthreads();

        // ======== slot 3: Y.P3 (L0 MLP2 + v'=v1*ss) ; cvt Z -> Lsx ; sOut(X) ========
        if (yv) {
#pragma unroll
            for (int m = 0; m < 2; ++m) {
                const int mr = m << 4;
                f32x4 sg = zero4(), ssa = zero4();
#pragma unroll
                for (int kt = 0; kt < 4; ++kt) {
                    bf16x8 a = afrag(lds + S1_OFF, 256, mr + l15, (kt << 6) + kbb);
                    sg  = MF(a, w2g0[kt], sg);
                    ssa = MF(a, w2s0[kt], ssa);
                }
#pragma unroll
                for (int e = 0; e < 4; ++e) {
                    int row = mr + (lg << 2) + e;
                    int swz = (row & 7) << 4;
                    *(unsigned short*)(Lsy + H_OFF + row * 512 + ((grow << 1) ^ swz)) = f2bu(sg[e] + b2g0);
                    float ssv = ssa[e] + b2s0;
#pragma unroll
                    for (int d = 0; d < 3; ++d)
                        *(unsigned short*)(Lsy + VIN_OFF + (d << 13) + row * 256 +
                            ((grow << 1) ^ swz)) = f2bu(v1a[m][d][e] * ssv);
                }
            }
        }
        if (zv) cvt_tile(lds, Lsx, tid);
        if (xv && tid < 32) {
            float s = 0.f;
#pragma unroll
            for (int w = 0; w < 8; ++w) s += *((float*)(lds + RED_OFF) + (w << 5) + tid);
            sOut[((ty - stride) << 5) + tid] = s + cf;
        }
        __syncthreads();
    }
}

// Dense masked pooling: y[b] = sum_a batch[b,a] * s_out[a]
__global__ __launch_bounds__(256) void eqsc_pool(const float* __restrict__ batch,
                                                 const float* __restrict__ s,
                                                 float* __restrict__ out,
                                                 int NA, int B, int CH)
{
    int b  = blockIdx.x % B;
    int ch = blockIdx.x / B;
    int a0 = ch * CH;
    int a1 = min(a0 + CH, NA);
    const float* br = batch + (size_t)b * NA;
    float acc = 0.f;
    for (int a = a0 + (threadIdx.x << 2); a < a1; a += 256 * 4) {
        f32x4 bb = *(const f32x4*)(br + a);
        f32x4 sv = *(const f32x4*)(s + a);
        acc += bb[0] * sv[0] + bb[1] * sv[1] + bb[2] * sv[2] + bb[3] * sv[3];
    }
#pragma unroll
    for (int off = 32; off > 0; off >>= 1) acc += __shfl_down(acc, off);
    __shared__ float wsum[4];
    if ((threadIdx.x & 63) == 0) wsum[threadIdx.x >> 6] = acc;
    __syncthreads();
    if (threadIdx.x == 0) atomicAdd(&out[b], wsum[0] + wsum[1] + wsum[2] + wsum[3]);
}

extern "C" void kernel_launch(void* const* d_in, const int* in_sizes, int n_in,
                              void* d_out, int out_size, void* d_ws, size_t ws_size,
                              hipStream_t stream)
{
    const float* S     = (const float*)d_in[0];
    const float* V     = (const float*)d_in[1];
    // d_in[2] = pos, unused by the reference
    const float* batch = (const float*)d_in[3];
    const float* u0w   = (const float*)d_in[4];
    const float* v0w   = (const float*)d_in[5];
    const float* a0w1  = (const float*)d_in[6];
    const float* a0b1  = (const float*)d_in[7];
    const float* a0w2  = (const float*)d_in[8];
    const float* a0b2  = (const float*)d_in[9];
    const float* u1w   = (const float*)d_in[10];
    const float* v1w   = (const float*)d_in[11];
    const float* a1w1  = (const float*)d_in[12];
    const float* a1b1  = (const float*)d_in[13];
    const float* a1w2  = (const float*)d_in[14];
    const float* a1b2  = (const float*)d_in[15];
    const float* outw  = (const float*)d_in[16];
    const float* outb  = (const float*)d_in[17];

    const int NA = in_sizes[0] / 128;
    const int NT = NA / 32;                  // 32 atoms per tile (200000/32 = 6250)
    const int B  = in_sizes[3] / NA;
    float* sAtom = (float*)d_ws;

    hipMemsetAsync(d_out, 0, (size_t)out_size * sizeof(float), stream);

    eqsc_main<<<256, 512, 0, stream>>>(S, V, u0w, v0w, a0w1, a0b1, a0w2, a0b2,
                                       u1w, v1w, a1w1, a1b1, a1w2, a1b2,
                                       outw, outb, sAtom, NT);

    const int CH  = 16384;
    const int NCH = (NA + CH - 1) / CH;
    eqsc_pool<<<B * NCH, 256, 0, stream>>>(batch, sAtom, (float*)d_out, NA, B, CH);
}